// Round 9
// baseline (2051.939 us; speedup 1.0000x reference)
//
#include <hip/hip_runtime.h>

#define T_LEN 4096
#define B_SZ  256

typedef float v2f __attribute__((ext_vector_type(2)));
typedef float v4f __attribute__((ext_vector_type(4)));

__device__ __forceinline__ float fexp2(float x) { return __builtin_amdgcn_exp2f(x); }
__device__ __forceinline__ float frcp(float x)  { return __builtin_amdgcn_rcpf(x); }

// DPP row_ror:S (S=1..15): lane l <- lane (l-S)&15 within its 16-lane row.
template<int S>
__device__ __forceinline__ float rorN(float v) {
    return __int_as_float(__builtin_amdgcn_update_dpp(
        0, __float_as_int(v), 0x120 + S, 0xf, 0xf, true));
}

// Inline-asm vm ops: RA cannot rematerialize an asm result (rounds 5/6
// proved plain loads get re-emitted at their uses), and an all-asm vm
// stream makes manual s_waitcnt vmcnt(N) counts exact.
template<int OFF>
__device__ __forceinline__ v4f aload(const float* p) {
    v4f r;
    asm volatile("global_load_dwordx4 %0, %1, off offset:%2"
                 : "=v"(r) : "v"(p), "i"(OFF) : "memory");
    return r;
}
__device__ __forceinline__ void aatomic(float* p, float v) {
    asm volatile("global_atomic_add_f32 %0, %1, off"
                 :: "v"(p), "v"(v) : "memory");
}

// ---------------------------------------------------------------------------
// Init: y1 <- bl1 broadcast, out <- bl2 broadcast. Recurrent kernels
// atomic-add their projected h contributions on top.
// ---------------------------------------------------------------------------
__global__ void init_bias_kernel(const float* __restrict__ bl1,
                                 const float* __restrict__ bl2,
                                 float* __restrict__ y1,
                                 float* __restrict__ out)
{
    const long idx = (long)blockIdx.x * blockDim.x + threadIdx.x; // over B*T
    float4 a1 = make_float4(bl1[0], bl1[1], bl1[2], bl1[3]);
    float4 b1 = make_float4(bl1[4], bl1[5], bl1[6], bl1[7]);
    float4 a2 = make_float4(bl2[0], bl2[1], bl2[2], bl2[3]);
    float4 b2 = make_float4(bl2[4], bl2[5], bl2[6], bl2[7]);
    float4* y4 = (float4*)y1;
    float4* o4 = (float4*)out;
    y4[idx * 2 + 0] = a1;
    y4[idx * 2 + 1] = b1;
    o4[idx * 2 + 0] = a2;
    o4[idx * 2 + 1] = b2;
}

// ---------------------------------------------------------------------------
// Recurrence. ROUND-9: each 16-lane DPP row carries TWO independent cells
// (P,Q) of the same direction; their steps are emitted back-to-back so the
// scheduler fills one chain's dependency stalls with the other's issue
// (round-8's 295 cyc/step was chain-stall-bound with nothing to issue).
// Weights are direction-uniform -> shared between P and Q. 8 cells/wave,
// 64 blocks (32 fwd + 32 bwd). Lane cl: unit j=cl&7, half=cl>>3; each lane
// computes (i_j,f_j) [half0] or (g_j,o_j) [half1] packed <2 x float>.
// h is period-8 replicated; DPP row_ror does the broadcast (no LDS).
// x arrives via an asm-load ring (3 groups; group = 2 steps x 2 cells =
// 8 x v4f), lookahead 2 groups, exact manual vmcnt. Output projection
// fused as asm atomics of h_{t-1} (Wc pre-halved, all lanes).
// ---------------------------------------------------------------------------
template<int ST>
__device__ __forceinline__ void rec_body(
    const float* x,    // [B,T,8] layer input
    const float* Wih,  // [32,8]
    const float* Whh,  // [32,8]
    const float* bias, // [32]
    const float* Wp,   // [8,16] output linear
    int dcol,          // 0 fwd, 8 bwd
    float* y,          // [B,T,8], pre-inited with bias
    int b0)            // base batch of this block (8 cells: b0..b0+7)
{
    const int tid  = threadIdx.x;
    const int cl   = tid & 15;
    const int j    = cl & 7;
    const int half = cl >> 3;
    const int bP   = b0 + 2 * (tid >> 4);
    const int bQ   = bP + 1;

    const int rA = half * 16 + j;        // half0: i-row j   | half1: g-row 16+j
    const int rB = half * 16 + 8 + j;    // half0: f-row 8+j | half1: o-row 24+j

    const float NL2E = -1.4426950408889634f;
    const float GSC  = 2.0f * NL2E;
    const float sA   = half ? GSC : NL2E;     // g-row gets tanh pre-scale
    const float sB   = NL2E;
    const float aselA = half ? 2.0f : 1.0f;   // tanh(u)=2*sigma(2u)-1 on half1
    const float bselA = half ? -1.0f : 0.0f;

    // Per-lane constants (shared by P and Q): matvec weights permuted by
    // rotation index; projection weights halved (both halves atomic).
    v2f Whk[8], Wik[8];
    float Wcp[8];
    #pragma unroll
    for (int s = 0; s < 8; ++s) {
        const int k = (j - s) & 7;
        Whk[s] = (v2f){Whh[rA * 8 + k] * sA, Whh[rB * 8 + k] * sB};
        Wcp[s] = Wp[j * 16 + dcol + k] * 0.5f;
    }
    #pragma unroll
    for (int k = 0; k < 8; ++k)
        Wik[k] = (v2f){Wih[rA * 8 + k] * sA, Wih[rB * 8 + k] * sB};
    const v2f bpk = (v2f){bias[rA] * sA, bias[rB] * sB};

    const int start = (ST > 0) ? 0 : (T_LEN - 1);
    const float* xpP = x + ((long)bP * T_LEN + start) * 8;
    const float* xpQ = x + ((long)bQ * T_LEN + start) * 8;
    float*       wpP = y + ((long)bP * T_LEN + start) * 8 + j;
    float*       wpQ = y + ((long)bQ * T_LEN + start) * 8 + j;

    float cP = 0.0f, hP = 0.0f, cQ = 0.0f, hQ = 0.0f;

    auto step = [&](v4f xa, v4f xb, float& c, float& h, float*& wp,
                    bool doProj) {
        // input projection (no h dependence)
        v2f ip = bpk;
        ip = __builtin_elementwise_fma(Wik[0], (v2f){xa.x, xa.x}, ip);
        ip = __builtin_elementwise_fma(Wik[1], (v2f){xa.y, xa.y}, ip);
        ip = __builtin_elementwise_fma(Wik[2], (v2f){xa.z, xa.z}, ip);
        ip = __builtin_elementwise_fma(Wik[3], (v2f){xa.w, xa.w}, ip);
        ip = __builtin_elementwise_fma(Wik[4], (v2f){xb.x, xb.x}, ip);
        ip = __builtin_elementwise_fma(Wik[5], (v2f){xb.y, xb.y}, ip);
        ip = __builtin_elementwise_fma(Wik[6], (v2f){xb.z, xb.z}, ip);
        ip = __builtin_elementwise_fma(Wik[7], (v2f){xb.w, xb.w}, ip);

        // 7 independent VALU rotations of h (h_{t-1})
        float hr0 = h;
        float hr1 = rorN<1>(h);
        float hr2 = rorN<2>(h);
        float hr3 = rorN<3>(h);
        float hr4 = rorN<4>(h);
        float hr5 = rorN<5>(h);
        float hr6 = rorN<6>(h);
        float hr7 = rorN<7>(h);

        // hidden matvec: two parallel pk chains, one seeded with input proj
        v2f a0 = ip, a1 = {0.0f, 0.0f};
        a0 = __builtin_elementwise_fma(Whk[0], (v2f){hr0, hr0}, a0);
        a1 = __builtin_elementwise_fma(Whk[1], (v2f){hr1, hr1}, a1);
        a0 = __builtin_elementwise_fma(Whk[2], (v2f){hr2, hr2}, a0);
        a1 = __builtin_elementwise_fma(Whk[3], (v2f){hr3, hr3}, a1);
        a0 = __builtin_elementwise_fma(Whk[4], (v2f){hr4, hr4}, a0);
        a1 = __builtin_elementwise_fma(Whk[5], (v2f){hr5, hr5}, a1);
        a0 = __builtin_elementwise_fma(Whk[6], (v2f){hr6, hr6}, a0);
        a1 = __builtin_elementwise_fma(Whk[7], (v2f){hr7, hr7}, a1);
        const v2f z = a0 + a1;

        // fused output projection of h_{t-1} (off-chain, all lanes)
        if (doProj) {
            float pa = hr0 * Wcp[0];
            pa = fmaf(hr1, Wcp[1], pa);
            pa = fmaf(hr2, Wcp[2], pa);
            pa = fmaf(hr3, Wcp[3], pa);
            pa = fmaf(hr4, Wcp[4], pa);
            pa = fmaf(hr5, Wcp[5], pa);
            pa = fmaf(hr6, Wcp[6], pa);
            pa = fmaf(hr7, Wcp[7], pa);
            aatomic(wp, pa);
            wp += ST * 8;
        }

        // activations
        const float vA = fmaf(frcp(1.0f + fexp2(z.x)), aselA, bselA);
        const float vB = frcp(1.0f + fexp2(z.y));

        // cross-half gate exchange (row_ror:8 swaps the two 8-lane halves)
        const float pAx = rorN<8>(vA);
        const float pBx = rorN<8>(vB);
        const float gi = half ? pAx : vA;
        const float gf = half ? pBx : vB;
        const float gg = half ? vA  : pAx;
        const float go = half ? vB  : pBx;

        c = fmaf(gf, c, gi * gg);
        const float th = fmaf(frcp(1.0f + fexp2(c * GSC)), 2.0f, -1.0f);
        h = go * th;
    };

    // Ring: 3 groups; group = 2 steps x 2 cells = 8 x v4f.
    // Layout: R0,R1 = P step t; R2,R3 = P step t+1; R4,R5 = Q t; R6,R7 = Q t+1.
    v4f A0, A1, A2, A3, A4, A5, A6, A7;
    v4f B0, B1, B2, B3, B4, B5, B6, B7;
    v4f C0, C1, C2, C3, C4, C5, C6, C7;

#define AREGS A0, A1, A2, A3, A4, A5, A6, A7
#define BREGS B0, B1, B2, B3, B4, B5, B6, B7
#define CREGS C0, C1, C2, C3, C4, C5, C6, C7

#define LOADG_I(P0, P1, P2, P3, P4, P5, P6, P7)                                \
    P0 = aload<0>(xpP);       P1 = aload<16>(xpP);                             \
    P2 = aload<ST * 32>(xpP); P3 = aload<ST * 32 + 16>(xpP);                   \
    P4 = aload<0>(xpQ);       P5 = aload<16>(xpQ);                             \
    P6 = aload<ST * 32>(xpQ); P7 = aload<ST * 32 + 16>(xpQ);                   \
    xpP += ST * 16;           xpQ += ST * 16;
#define LOADG(REGS) LOADG_I(REGS)

#define WAITG_I(N, P0, P1, P2, P3, P4, P5, P6, P7)                             \
    asm volatile("s_waitcnt vmcnt(" #N ")"                                     \
        : "+v"(P0), "+v"(P1), "+v"(P2), "+v"(P3),                              \
          "+v"(P4), "+v"(P5), "+v"(P6), "+v"(P7) :: "memory")
#define WAITG(N, REGS) WAITG_I(N, REGS)

// Group = 2 steps for P and Q, P/Q steps adjacent so the scheduler
// interleaves the two independent chains.
#define GROUP2_I(P0, P1, P2, P3, P4, P5, P6, P7, FIRSTPROJ)                    \
    step(P0, P1, cP, hP, wpP, FIRSTPROJ);                                      \
    step(P4, P5, cQ, hQ, wpQ, FIRSTPROJ);                                      \
    step(P2, P3, cP, hP, wpP, true);                                           \
    step(P6, P7, cQ, hQ, wpQ, true);
#define GROUP2(REGS, FIRSTPROJ) GROUP2_I(REGS, FIRSTPROJ)

    // drain compiler-issued (weight) loads so asm vm counts are exact
    asm volatile("s_waitcnt vmcnt(0)" ::: "memory");

    // 2048 groups of 2 timesteps. Per group: 8 loads + 4 atomics (M0: 2).
    LOADG(AREGS)                       // G-L0
    LOADG(BREGS)                       // G-L1
    LOADG(CREGS)                       // G-L2
    WAITG(16, AREGS); GROUP2(AREGS, false)    // M0 (2 atomics)
    LOADG(AREGS)                       // G-L3
    WAITG(18, BREGS); GROUP2(BREGS, true)     // M1 (4 atomics)
    LOADG(BREGS)                       // G-L4
    WAITG(22, CREGS); GROUP2(CREGS, true)     // M2

    for (int i = 0; i < 681; ++i) {    // M3..M2045, loads L5..L2047
        LOADG(CREGS) WAITG(24, AREGS); GROUP2(AREGS, true)
        LOADG(AREGS) WAITG(24, BREGS); GROUP2(BREGS, true)
        LOADG(BREGS) WAITG(24, CREGS); GROUP2(CREGS, true)
    }
    WAITG(16, AREGS); GROUP2(AREGS, true)     // M2046
    WAITG(8,  BREGS); GROUP2(BREGS, true)     // M2047

#undef LOADG
#undef LOADG_I
#undef GROUP2
#undef GROUP2_I
#undef WAITG
#undef WAITG_I
#undef AREGS
#undef BREGS
#undef CREGS

    // tail: projection of the final h for both cells
    {
        float pa = hP * Wcp[0];
        pa = fmaf(rorN<1>(hP), Wcp[1], pa);
        pa = fmaf(rorN<2>(hP), Wcp[2], pa);
        pa = fmaf(rorN<3>(hP), Wcp[3], pa);
        pa = fmaf(rorN<4>(hP), Wcp[4], pa);
        pa = fmaf(rorN<5>(hP), Wcp[5], pa);
        pa = fmaf(rorN<6>(hP), Wcp[6], pa);
        pa = fmaf(rorN<7>(hP), Wcp[7], pa);
        aatomic(wpP, pa);
        float qa = hQ * Wcp[0];
        qa = fmaf(rorN<1>(hQ), Wcp[1], qa);
        qa = fmaf(rorN<2>(hQ), Wcp[2], qa);
        qa = fmaf(rorN<3>(hQ), Wcp[3], qa);
        qa = fmaf(rorN<4>(hQ), Wcp[4], qa);
        qa = fmaf(rorN<5>(hQ), Wcp[5], qa);
        qa = fmaf(rorN<6>(hQ), Wcp[6], qa);
        qa = fmaf(rorN<7>(hQ), Wcp[7], qa);
        aatomic(wpQ, qa);
    }
}

__global__ __launch_bounds__(64, 1)
void lstm_rec_kernel(const float* __restrict__ x,
                     const float* __restrict__ WihF, const float* __restrict__ WhhF,
                     const float* __restrict__ bF,
                     const float* __restrict__ WihB, const float* __restrict__ WhhB,
                     const float* __restrict__ bB,
                     const float* __restrict__ Wp,
                     float* __restrict__ y)
{
    if (blockIdx.x < 32)
        rec_body<1 >(x, WihF, WhhF, bF, Wp, 0, y, 8 * (int)blockIdx.x);
    else
        rec_body<-1>(x, WihB, WhhB, bB, Wp, 8, y, 8 * ((int)blockIdx.x - 32));
}

extern "C" void kernel_launch(void* const* d_in, const int* in_sizes, int n_in,
                              void* d_out, int out_size, void* d_ws, size_t ws_size,
                              hipStream_t stream)
{
    const float* x     = (const float*)d_in[0];
    const float* Wih1f = (const float*)d_in[1];
    const float* Whh1f = (const float*)d_in[2];
    const float* b1f   = (const float*)d_in[3];
    const float* Wih1b = (const float*)d_in[4];
    const float* Whh1b = (const float*)d_in[5];
    const float* b1b   = (const float*)d_in[6];
    const float* Wih2f = (const float*)d_in[7];
    const float* Whh2f = (const float*)d_in[8];
    const float* b2f   = (const float*)d_in[9];
    const float* Wih2b = (const float*)d_in[10];
    const float* Whh2b = (const float*)d_in[11];
    const float* b2b   = (const float*)d_in[12];
    const float* W1    = (const float*)d_in[13];
    const float* bl1   = (const float*)d_in[14];
    const float* W2    = (const float*)d_in[15];
    const float* bl2   = (const float*)d_in[16];

    float* out = (float*)d_out;
    float* y1  = (float*)d_ws;   // [B,T,8] fp32 = 32 MB (proven-safe ws budget)

    const int BT = B_SZ * T_LEN;

    init_bias_kernel<<<BT / 256, 256, 0, stream>>>(bl1, bl2, y1, out);

    lstm_rec_kernel<<<64, 64, 0, stream>>>(x, Wih1f, Whh1f, b1f,
                                           Wih1b, Whh1b, b1b, W1, y1);

    lstm_rec_kernel<<<64, 64, 0, stream>>>(y1, Wih2f, Whh2f, b2f,
                                           Wih2b, Whh2b, b2b, W2, out);
}